// Round 13
// baseline (87.109 us; speedup 1.0000x reference)
//
#include <hip/hip_runtime.h>

#define Nn 1024
#define Cc 23
#define Hh 100
#define KN 128                 // knots over v=r/1.5 in [0,3], 127 cells
#define DSTR 132               // lds_d row stride (128 + pad)
#define MUSCALE 28.2222222f    // 127/4.5  (mu = r * MUSCALE)
#define MUCLAMP 126.999f
#define NBC 512                // megaconv blocks: z(4) x ah(2) x s(64)

// ws float offsets
#define UT_OFF     0           // U transposed [23][128] = 2944
#define WF1T_OFF   4096        // Wf1^T / 32  [30][1024] = 30720
#define G4_OFF     34816       // [4096][4] = 16384
#define BIAS_OFF   51200       // [4]
#define COLSUM_OFF 51204       // [30]
#define X1PRE_OFF  51264       // [30][4] atomic accumulators = 120
#define CTR_OFF    51392       // 1 uint ticket

__device__ __forceinline__ float rdlane(float v, int l) {
    return __int_as_float(__builtin_amdgcn_readlane(__float_as_int(v), l));
}

// ---------------------------------------------------------------------------
// K0: 179 blocks.
//  0..127 : U_T[c][k] (one knot per block; W2 LDS-staged, coalesced)
//  128..143: geom4 pack
//  144..147: bias[z]
//  148    : colsum[d] + zero x1pre + zero ticket
//  149..178: Wf1T[d][k] = Wf1[k][d]/32
// ---------------------------------------------------------------------------
__global__ __launch_bounds__(256)
void prep_kernel(const float* __restrict__ f,
                 const float* __restrict__ geom,
                 const float* __restrict__ W1,
                 const float* __restrict__ b1,
                 const float* __restrict__ W2,
                 const float* __restrict__ b2,
                 const float* __restrict__ Wf1,
                 float* __restrict__ ws) {
    int blk = blockIdx.x;
    int t = threadIdx.x;
    if (blk < 128) {
        __shared__ float w2s[Hh * Cc];
        __shared__ float hv_s[Hh];
        int k = blk;
        for (int j = t; j < Hh * Cc; j += 256) w2s[j] = W2[j];
        if (t < Hh) {
            float v = (float)k * (3.0f / 127.0f);
            const float HPI = 1.57079632679f;
            float c0 = cosf(HPI * v);
            float c1 = cosf(HPI * (v - 1.0f));
            float c2 = cosf(HPI * (v - 2.0f));
            float s0 = (v < 1.0f) ? c0 * c0 : 0.0f;
            float s1 = (fabsf(v - 1.0f) < 1.0f) ? c1 * c1 : 0.0f;
            float s2 = (v > 1.0f && v < 3.0f) ? c2 * c2 : 0.0f;
            float pre = fmaf(s0, W1[t],
                         fmaf(s1, W1[Hh + t],
                          fmaf(s2, W1[2 * Hh + t], b1[t])));
            hv_s[t] = fmaxf(pre, 0.f);
        }
        __syncthreads();
        if (t < Cc) {
            float a0 = 0.f, a1 = 0.f;
            #pragma unroll 4
            for (int h = 0; h < Hh; h += 2) {
                a0 = fmaf(hv_s[h],     w2s[h * Cc + t],       a0);
                a1 = fmaf(hv_s[h + 1], w2s[(h + 1) * Cc + t], a1);
            }
            ws[UT_OFF + t * KN + k] = a0 + a1;
        }
    } else if (blk < 144) {
        int zb = (blk - 128) * 256 + t;
        const float* g = geom + zb * 3;
        reinterpret_cast<float4*>(ws + G4_OFF)[zb] =
            make_float4(g[0], g[1], g[2], 0.f);
    } else if (blk < 148) {
        __shared__ float red[256];
        int z = blk - 144;
        float s = 0.f;
        #pragma unroll
        for (int rr = 0; rr < 4; ++rr) {
            const float* fr = f + ((z << 10) + rr * 256 + t) * Cc;
            #pragma unroll
            for (int c = 0; c < Cc; ++c) s = fmaf(fr[c], b2[c], s);
        }
        red[t] = s; __syncthreads();
        for (int off = 128; off; off >>= 1) {
            if (t < off) red[t] += red[t + off];
            __syncthreads();
        }
        if (t == 0) ws[BIAS_OFF + z] = red[0];
    } else if (blk == 148) {
        __shared__ float cs_s[240];
        if (t < 240) {
            int d = t % 30, oct = t / 30;
            float c0 = 0.f, c1 = 0.f;
            #pragma unroll 4
            for (int j = 0; j < 128; j += 2) {
                c0 += Wf1[(oct * 128 + j) * 30 + d];
                c1 += Wf1[(oct * 128 + j + 1) * 30 + d];
            }
            cs_s[t] = c0 + c1;
        }
        __syncthreads();
        if (t < 30) {
            float cs = 0.f;
            #pragma unroll
            for (int o = 0; o < 8; ++o) cs += cs_s[o * 30 + t];
            ws[COLSUM_OFF + t] = cs;
        }
        if (t < 120) ws[X1PRE_OFF + t] = 0.f;    // zero accumulators
        if (t == 120) reinterpret_cast<unsigned*>(ws + CTR_OFF)[0] = 0u;
    } else {
        int d = blk - 149;
        #pragma unroll
        for (int j = 0; j < 4; ++j) {
            int k = j * 256 + t;
            ws[WF1T_OFF + d * Nn + k] = Wf1[k * 30 + d] * 0.03125f;
        }
    }
}

// ---------------------------------------------------------------------------
// K1: megaconv. 512 blocks x 256 thr. Block (z, ah, s): a-range ah*512..+511
// (2 a's per thread), b-range s*16..+15.
//  - D-build for 16 b rows into LDS (readlane f broadcasts, no s_load chains)
//  - 32 lerp-edges per thread
//  - fold accs through Wf1T -> atomicAdd x1pre[d][z]
//  - ticket; the 512th block runs fc2/fc3 inline and writes out[4]
// ---------------------------------------------------------------------------
__global__ __launch_bounds__(256, 2)
void megaconv_kernel(const float* __restrict__ f,
                     const float* __restrict__ geom,
                     const float* __restrict__ ut,       // ws + UT_OFF
                     const float4* __restrict__ geom4,   // ws + G4_OFF
                     const float4* __restrict__ wf1t4,   // ws + WF1T_OFF
                     float* __restrict__ ws,
                     const float* __restrict__ bf1,
                     const float* __restrict__ Wf2, const float* __restrict__ bf2,
                     const float* __restrict__ Wf3, const float* __restrict__ bf3,
                     float* __restrict__ out) {
    __shared__ float lds_d[16 * DSTR];   // 8448 B (aliased: acc staging, tail)
    __shared__ int lastflag;
    const int bid = blockIdx.x;
    const int t = threadIdx.x;
    const int lane = t & 63;
    const int wv = __builtin_amdgcn_readfirstlane(t >> 6);
    const int z = bid >> 7;
    const int ah = (bid >> 6) & 1;
    const int s = bid & 63;
    const int b0 = s * 16;
    const int k = t & 127;
    const int rh = __builtin_amdgcn_readfirstlane(t >> 7);   // row half 0/1

    // staging (all coalesced / per-lane)
    float ur[Cc];
    #pragma unroll
    for (int c = 0; c < Cc; ++c) ur[c] = ut[c * KN + k];
    float fr[3];                           // 8 rows x 23 f-values per wave-half
    {
        int base = ((z << 10) + b0 + rh * 8) * Cc;
        #pragma unroll
        for (int j = 0; j < 3; ++j) {
            int off = j * 64 + lane;
            if (off > 183) off = 183;
            fr[j] = f[base + off];
        }
    }
    float gr;                              // 16 b-geometries (48 floats)
    {
        int off = lane < 48 ? lane : 47;
        gr = geom[((z << 10) + b0) * 3 + off];
    }
    float4 ga0 = geom4[(z << 10) + (ah << 9) + t];
    float4 ga1 = geom4[(z << 10) + (ah << 9) + 256 + t];

    // D-build: 8 rows per wave-half, f broadcast via readlane
    #pragma unroll
    for (int r = 0; r < 8; ++r) {
        float a0 = 0.f, a1 = 0.f, a2 = 0.f, a3 = 0.f;
        #pragma unroll
        for (int c = 0; c < 20; c += 4) {
            a0 = fmaf(rdlane(fr[(r * Cc + c + 0) >> 6], (r * Cc + c + 0) & 63), ur[c + 0], a0);
            a1 = fmaf(rdlane(fr[(r * Cc + c + 1) >> 6], (r * Cc + c + 1) & 63), ur[c + 1], a1);
            a2 = fmaf(rdlane(fr[(r * Cc + c + 2) >> 6], (r * Cc + c + 2) & 63), ur[c + 2], a2);
            a3 = fmaf(rdlane(fr[(r * Cc + c + 3) >> 6], (r * Cc + c + 3) & 63), ur[c + 3], a3);
        }
        a0 = fmaf(rdlane(fr[(r * Cc + 20) >> 6], (r * Cc + 20) & 63), ur[20], a0);
        a1 = fmaf(rdlane(fr[(r * Cc + 21) >> 6], (r * Cc + 21) & 63), ur[21], a1);
        a2 = fmaf(rdlane(fr[(r * Cc + 22) >> 6], (r * Cc + 22) & 63), ur[22], a2);
        lds_d[(rh * 8 + r) * DSTR + k] = (a0 + a1) + (a2 + a3);
    }
    __syncthreads();

    // edges: 2 a's x 16 b's per thread
    float acc0 = 0.f, acc1 = 0.f;
    #pragma unroll
    for (int bl = 0; bl < 16; ++bl) {
        float gbx = rdlane(gr, bl * 3 + 0);
        float gby = rdlane(gr, bl * 3 + 1);
        float gbz = rdlane(gr, bl * 3 + 2);
        const float* row = lds_d + bl * DSTR;
        {
            float dx = ga0.x - gbx, dy = ga0.y - gby, dz = ga0.z - gbz;
            float r = sqrtf(fmaf(dx, dx, fmaf(dy, dy, fmaf(dz, dz, 1e-12f))));
            float mu = fminf(r * MUSCALE, MUCLAMP);
            int m = (int)mu;
            float tt = mu - (float)m;
            float d0 = row[m];
            float d1 = row[m + 1];
            acc0 += fmaf(tt, d1 - d0, d0);
        }
        {
            float dx = ga1.x - gbx, dy = ga1.y - gby, dz = ga1.z - gbz;
            float r = sqrtf(fmaf(dx, dx, fmaf(dy, dy, fmaf(dz, dz, 1e-12f))));
            float mu = fminf(r * MUSCALE, MUCLAMP);
            int m = (int)mu;
            float tt = mu - (float)m;
            float d0 = row[m];
            float d1 = row[m + 1];
            acc1 += fmaf(tt, d1 - d0, d0);
        }
    }
    __syncthreads();

    // fold: 512 accs -> 30 per-(d,z) atomic adds via Wf1T
    lds_d[t] = acc0;
    lds_d[256 + t] = acc1;
    __syncthreads();
    {
        const float4* a4 = reinterpret_cast<const float4*>(lds_d);
        float4 av0 = a4[lane];                    // a-local 4*lane..+3
        float4 av1 = a4[64 + lane];               // a-local 256+4*lane..+3
        #pragma unroll
        for (int i = 0; i < 8; ++i) {
            int d = wv + 4 * i;
            if (d < 30) {
                float4 w0 = wf1t4[d * 256 + (ah << 7) + lane];
                float4 w1 = wf1t4[d * 256 + (ah << 7) + 64 + lane];
                float sum = av0.x * w0.x + av0.y * w0.y + av0.z * w0.z + av0.w * w0.w
                          + av1.x * w1.x + av1.y * w1.y + av1.z * w1.z + av1.w * w1.w;
                #pragma unroll
                for (int off = 32; off; off >>= 1) sum += __shfl_down(sum, off);
                if (lane == 0) atomicAdd(&ws[X1PRE_OFF + d * 4 + z], sum);
            }
        }
    }

    // ticket: last block (everyone else already done) runs the head
    __syncthreads();
    if (t == 0) {
        unsigned* ctr = reinterpret_cast<unsigned*>(ws + CTR_OFF);
        unsigned r = __hip_atomic_fetch_add(ctr, 1u, __ATOMIC_ACQ_REL,
                                            __HIP_MEMORY_SCOPE_AGENT);
        lastflag = (r == NBC - 1) ? 1 : 0;
    }
    __syncthreads();
    if (!lastflag) return;

    // -------- fc23 tail (one block) --------
    float* x1s = lds_d;          // [120]
    float* x2s = lds_d + 128;    // [40]
    if (t < 120) {
        int zz = t & 3, d = t >> 2;          // t = d*4+zz
        float x1 = ws[X1PRE_OFF + t]
                 + ws[BIAS_OFF + zz] * 0.03125f * ws[COLSUM_OFF + d]
                 + bf1[d];
        x1s[zz * 30 + d] = fmaxf(x1, 0.f);
    }
    __syncthreads();
    if (t < 40) {
        int zz = t / 10, d = t % 10;
        float sm = bf2[d];
        #pragma unroll
        for (int kk = 0; kk < 30; ++kk)
            sm = fmaf(x1s[zz * 30 + kk], Wf2[kk * 10 + d], sm);
        x2s[t] = fmaxf(sm, 0.f);
    }
    __syncthreads();
    if (t < 4) {
        float sm = bf3[0];
        #pragma unroll
        for (int kk = 0; kk < 10; ++kk)
            sm = fmaf(x2s[t * 10 + kk], Wf3[kk], sm);
        out[t] = sm;
    }
}

extern "C" void kernel_launch(void* const* d_in, const int* in_sizes, int n_in,
                              void* d_out, int out_size, void* d_ws, size_t ws_size,
                              hipStream_t stream) {
    const float* f   = (const float*)d_in[0];
    const float* geo = (const float*)d_in[1];
    const float* W1  = (const float*)d_in[2];
    const float* b1  = (const float*)d_in[3];
    const float* W2  = (const float*)d_in[4];
    const float* b2  = (const float*)d_in[5];
    const float* Wf1 = (const float*)d_in[6];
    const float* bf1 = (const float*)d_in[7];
    const float* Wf2 = (const float*)d_in[8];
    const float* bf2 = (const float*)d_in[9];
    const float* Wf3 = (const float*)d_in[10];
    const float* bf3 = (const float*)d_in[11];
    float* ws  = (float*)d_ws;
    float* out = (float*)d_out;

    hipLaunchKernelGGL(prep_kernel, dim3(179), dim3(256), 0, stream,
                       f, geo, W1, b1, W2, b2, Wf1, ws);
    hipLaunchKernelGGL(megaconv_kernel, dim3(NBC), dim3(256), 0, stream,
                       f, geo, ws + UT_OFF,
                       reinterpret_cast<const float4*>(ws + G4_OFF),
                       reinterpret_cast<const float4*>(ws + WF1T_OFF),
                       ws, bf1, Wf2, bf2, Wf3, bf3, out);
}

// Round 14
// 33.234 us; speedup vs baseline: 2.6211x; 2.6211x over previous
//
#include <hip/hip_runtime.h>

#define Nn 1024
#define Cc 23
#define Hh 100
#define KN 128                 // knots over v=r/1.5 in [0,3], 127 cells
#define DSTR 132               // lds_d row stride (128 + pad)
#define MUSCALE 28.2222222f    // 127/4.5  (mu = r * MUSCALE)
#define MUCLAMP 126.999f
#define NBC 512                // megaconv blocks: z(4) x ah(2) x s(64)

// ws float offsets
#define UT_OFF     0           // U transposed [23][128] = 2944
#define WF1T_OFF   4096        // Wf1^T / 32  [30][1024] = 30720
#define G4_OFF     34816       // [4096][4] = 16384
#define BIAS_OFF   51200       // [4]
#define COLSUM_OFF 51204       // [30]
#define CTR_OFF    51264       // 1 uint ticket (64B-aligned)
#define PB_OFF     51328       // [30][512] fc1 partials = 15360

__device__ __forceinline__ float rdlane(float v, int l) {
    return __int_as_float(__builtin_amdgcn_readlane(__float_as_int(v), l));
}

// ---------------------------------------------------------------------------
// K0: 179 blocks.
//  0..127 : U_T[c][k] (one knot per block; W2 LDS-staged, coalesced)
//  128..143: geom4 pack
//  144..147: bias[z]
//  148    : colsum[d] + zero ticket
//  149..178: Wf1T[d][k] = Wf1[k][d]/32
// ---------------------------------------------------------------------------
__global__ __launch_bounds__(256)
void prep_kernel(const float* __restrict__ f,
                 const float* __restrict__ geom,
                 const float* __restrict__ W1,
                 const float* __restrict__ b1,
                 const float* __restrict__ W2,
                 const float* __restrict__ b2,
                 const float* __restrict__ Wf1,
                 float* __restrict__ ws) {
    int blk = blockIdx.x;
    int t = threadIdx.x;
    if (blk < 128) {
        __shared__ float w2s[Hh * Cc];
        __shared__ float hv_s[Hh];
        int k = blk;
        for (int j = t; j < Hh * Cc; j += 256) w2s[j] = W2[j];
        if (t < Hh) {
            float v = (float)k * (3.0f / 127.0f);
            const float HPI = 1.57079632679f;
            float c0 = cosf(HPI * v);
            float c1 = cosf(HPI * (v - 1.0f));
            float c2 = cosf(HPI * (v - 2.0f));
            float s0 = (v < 1.0f) ? c0 * c0 : 0.0f;
            float s1 = (fabsf(v - 1.0f) < 1.0f) ? c1 * c1 : 0.0f;
            float s2 = (v > 1.0f && v < 3.0f) ? c2 * c2 : 0.0f;
            float pre = fmaf(s0, W1[t],
                         fmaf(s1, W1[Hh + t],
                          fmaf(s2, W1[2 * Hh + t], b1[t])));
            hv_s[t] = fmaxf(pre, 0.f);
        }
        __syncthreads();
        if (t < Cc) {
            float a0 = 0.f, a1 = 0.f;
            #pragma unroll 4
            for (int h = 0; h < Hh; h += 2) {
                a0 = fmaf(hv_s[h],     w2s[h * Cc + t],       a0);
                a1 = fmaf(hv_s[h + 1], w2s[(h + 1) * Cc + t], a1);
            }
            ws[UT_OFF + t * KN + k] = a0 + a1;
        }
    } else if (blk < 144) {
        int zb = (blk - 128) * 256 + t;
        const float* g = geom + zb * 3;
        reinterpret_cast<float4*>(ws + G4_OFF)[zb] =
            make_float4(g[0], g[1], g[2], 0.f);
    } else if (blk < 148) {
        __shared__ float red[256];
        int z = blk - 144;
        float s = 0.f;
        #pragma unroll
        for (int rr = 0; rr < 4; ++rr) {
            const float* fr = f + ((z << 10) + rr * 256 + t) * Cc;
            #pragma unroll
            for (int c = 0; c < Cc; ++c) s = fmaf(fr[c], b2[c], s);
        }
        red[t] = s; __syncthreads();
        for (int off = 128; off; off >>= 1) {
            if (t < off) red[t] += red[t + off];
            __syncthreads();
        }
        if (t == 0) ws[BIAS_OFF + z] = red[0];
    } else if (blk == 148) {
        __shared__ float cs_s[240];
        if (t < 240) {
            int d = t % 30, oct = t / 30;
            float c0 = 0.f, c1 = 0.f;
            #pragma unroll 4
            for (int j = 0; j < 128; j += 2) {
                c0 += Wf1[(oct * 128 + j) * 30 + d];
                c1 += Wf1[(oct * 128 + j + 1) * 30 + d];
            }
            cs_s[t] = c0 + c1;
        }
        __syncthreads();
        if (t < 30) {
            float cs = 0.f;
            #pragma unroll
            for (int o = 0; o < 8; ++o) cs += cs_s[o * 30 + t];
            ws[COLSUM_OFF + t] = cs;
        }
        if (t == 0) reinterpret_cast<unsigned*>(ws + CTR_OFF)[0] = 0u;
    } else {
        int d = blk - 149;
        #pragma unroll
        for (int j = 0; j < 4; ++j) {
            int k = j * 256 + t;
            ws[WF1T_OFF + d * Nn + k] = Wf1[k * 30 + d] * 0.03125f;
        }
    }
}

// ---------------------------------------------------------------------------
// K1: megaconv. 512 blocks x 256 thr. Block (z, ah, s): a-range ah*512..+511
// (2 a's per thread), b-range s*16..+15.
//  - D-build for 16 b rows into LDS (readlane f broadcasts)
//  - 32 lerp-edges per thread
//  - fold accs through Wf1T -> PLAIN stores pb[d][bid] (no contention)
//  - ticket (ACQ_REL); last block reduces pb + fc23 inline -> out[4]
// ---------------------------------------------------------------------------
__global__ __launch_bounds__(256, 2)
void megaconv_kernel(const float* __restrict__ f,
                     const float* __restrict__ geom,
                     const float* __restrict__ ut,       // ws + UT_OFF
                     const float4* __restrict__ geom4,   // ws + G4_OFF
                     const float4* __restrict__ wf1t4,   // ws + WF1T_OFF
                     float* __restrict__ ws,
                     const float* __restrict__ bf1,
                     const float* __restrict__ Wf2, const float* __restrict__ bf2,
                     const float* __restrict__ Wf3, const float* __restrict__ bf3,
                     float* __restrict__ out) {
    __shared__ float lds_d[16 * DSTR];   // 8448 B (aliased: acc staging, tail)
    __shared__ int lastflag;
    const int bid = blockIdx.x;
    const int t = threadIdx.x;
    const int lane = t & 63;
    const int wv = __builtin_amdgcn_readfirstlane(t >> 6);
    const int z = bid >> 7;
    const int ah = (bid >> 6) & 1;
    const int s = bid & 63;
    const int b0 = s * 16;
    const int k = t & 127;
    const int rh = __builtin_amdgcn_readfirstlane(t >> 7);   // row half 0/1

    // staging (all coalesced / per-lane)
    float ur[Cc];
    #pragma unroll
    for (int c = 0; c < Cc; ++c) ur[c] = ut[c * KN + k];
    float fr[3];                           // 8 rows x 23 f-values per wave-half
    {
        int base = ((z << 10) + b0 + rh * 8) * Cc;
        #pragma unroll
        for (int j = 0; j < 3; ++j) {
            int off = j * 64 + lane;
            if (off > 183) off = 183;
            fr[j] = f[base + off];
        }
    }
    float gr;                              // 16 b-geometries (48 floats)
    {
        int off = lane < 48 ? lane : 47;
        gr = geom[((z << 10) + b0) * 3 + off];
    }
    float4 ga0 = geom4[(z << 10) + (ah << 9) + t];
    float4 ga1 = geom4[(z << 10) + (ah << 9) + 256 + t];

    // D-build: 8 rows per wave-half, f broadcast via readlane
    #pragma unroll
    for (int r = 0; r < 8; ++r) {
        float a0 = 0.f, a1 = 0.f, a2 = 0.f, a3 = 0.f;
        #pragma unroll
        for (int c = 0; c < 20; c += 4) {
            a0 = fmaf(rdlane(fr[(r * Cc + c + 0) >> 6], (r * Cc + c + 0) & 63), ur[c + 0], a0);
            a1 = fmaf(rdlane(fr[(r * Cc + c + 1) >> 6], (r * Cc + c + 1) & 63), ur[c + 1], a1);
            a2 = fmaf(rdlane(fr[(r * Cc + c + 2) >> 6], (r * Cc + c + 2) & 63), ur[c + 2], a2);
            a3 = fmaf(rdlane(fr[(r * Cc + c + 3) >> 6], (r * Cc + c + 3) & 63), ur[c + 3], a3);
        }
        a0 = fmaf(rdlane(fr[(r * Cc + 20) >> 6], (r * Cc + 20) & 63), ur[20], a0);
        a1 = fmaf(rdlane(fr[(r * Cc + 21) >> 6], (r * Cc + 21) & 63), ur[21], a1);
        a2 = fmaf(rdlane(fr[(r * Cc + 22) >> 6], (r * Cc + 22) & 63), ur[22], a2);
        lds_d[(rh * 8 + r) * DSTR + k] = (a0 + a1) + (a2 + a3);
    }
    __syncthreads();

    // edges: 2 a's x 16 b's per thread
    float acc0 = 0.f, acc1 = 0.f;
    #pragma unroll
    for (int bl = 0; bl < 16; ++bl) {
        float gbx = rdlane(gr, bl * 3 + 0);
        float gby = rdlane(gr, bl * 3 + 1);
        float gbz = rdlane(gr, bl * 3 + 2);
        const float* row = lds_d + bl * DSTR;
        {
            float dx = ga0.x - gbx, dy = ga0.y - gby, dz = ga0.z - gbz;
            float r = sqrtf(fmaf(dx, dx, fmaf(dy, dy, fmaf(dz, dz, 1e-12f))));
            float mu = fminf(r * MUSCALE, MUCLAMP);
            int m = (int)mu;
            float tt = mu - (float)m;
            float d0 = row[m];
            float d1 = row[m + 1];
            acc0 += fmaf(tt, d1 - d0, d0);
        }
        {
            float dx = ga1.x - gbx, dy = ga1.y - gby, dz = ga1.z - gbz;
            float r = sqrtf(fmaf(dx, dx, fmaf(dy, dy, fmaf(dz, dz, 1e-12f))));
            float mu = fminf(r * MUSCALE, MUCLAMP);
            int m = (int)mu;
            float tt = mu - (float)m;
            float d0 = row[m];
            float d1 = row[m + 1];
            acc1 += fmaf(tt, d1 - d0, d0);
        }
    }
    __syncthreads();

    // fold: 512 accs -> 30 per-block partials, PLAIN stores (no contention)
    lds_d[t] = acc0;
    lds_d[256 + t] = acc1;
    __syncthreads();
    {
        const float4* a4 = reinterpret_cast<const float4*>(lds_d);
        float4 av0 = a4[lane];                    // a-local 4*lane..+3
        float4 av1 = a4[64 + lane];               // a-local 256+4*lane..+3
        #pragma unroll
        for (int i = 0; i < 8; ++i) {
            int d = wv + 4 * i;
            if (d < 30) {
                float4 w0 = wf1t4[d * 256 + (ah << 7) + lane];
                float4 w1 = wf1t4[d * 256 + (ah << 7) + 64 + lane];
                float sum = av0.x * w0.x + av0.y * w0.y + av0.z * w0.z + av0.w * w0.w
                          + av1.x * w1.x + av1.y * w1.y + av1.z * w1.z + av1.w * w1.w;
                #pragma unroll
                for (int off = 32; off; off >>= 1) sum += __shfl_down(sum, off);
                if (lane == 0) ws[PB_OFF + d * NBC + bid] = sum;
            }
        }
    }

    // ticket: last block (all others provably done) runs the head
    __syncthreads();
    if (t == 0) {
        unsigned* ctr = reinterpret_cast<unsigned*>(ws + CTR_OFF);
        unsigned r = __hip_atomic_fetch_add(ctr, 1u, __ATOMIC_ACQ_REL,
                                            __HIP_MEMORY_SCOPE_AGENT);
        lastflag = (r == NBC - 1) ? 1 : 0;
    }
    __syncthreads();
    if (!lastflag) return;

    // -------- tail: reduce pb -> x1 -> fc2 -> fc3 (one block) --------
    float* tb  = lds_d;          // [240]
    float* x1s = lds_d + 256;    // [120]
    float* x2s = lds_d + 384;    // [40]
    if (t < 240) {
        int d = t >> 3, sub = t & 7;      // sub = z*2 + part
        const float4* p4 = reinterpret_cast<const float4*>(
            ws + PB_OFF + d * NBC + sub * 64);
        float s0 = 0.f, s1 = 0.f, s2 = 0.f, s3 = 0.f;
        #pragma unroll
        for (int j = 0; j < 16; ++j) {
            float4 v = p4[j];
            s0 += v.x; s1 += v.y; s2 += v.z; s3 += v.w;
        }
        tb[t] = (s0 + s1) + (s2 + s3);
    }
    __syncthreads();
    if (t < 120) {
        int d = t >> 2, zz = t & 3;
        float x1 = tb[d * 8 + zz * 2] + tb[d * 8 + zz * 2 + 1]
                 + ws[BIAS_OFF + zz] * 0.03125f * ws[COLSUM_OFF + d]
                 + bf1[d];
        x1s[zz * 30 + d] = fmaxf(x1, 0.f);
    }
    __syncthreads();
    if (t < 40) {
        int zz = t / 10, d = t % 10;
        float sm = bf2[d];
        #pragma unroll
        for (int kk = 0; kk < 30; ++kk)
            sm = fmaf(x1s[zz * 30 + kk], Wf2[kk * 10 + d], sm);
        x2s[t] = fmaxf(sm, 0.f);
    }
    __syncthreads();
    if (t < 4) {
        float sm = bf3[0];
        #pragma unroll
        for (int kk = 0; kk < 10; ++kk)
            sm = fmaf(x2s[t * 10 + kk], Wf3[kk], sm);
        out[t] = sm;
    }
}

extern "C" void kernel_launch(void* const* d_in, const int* in_sizes, int n_in,
                              void* d_out, int out_size, void* d_ws, size_t ws_size,
                              hipStream_t stream) {
    const float* f   = (const float*)d_in[0];
    const float* geo = (const float*)d_in[1];
    const float* W1  = (const float*)d_in[2];
    const float* b1  = (const float*)d_in[3];
    const float* W2  = (const float*)d_in[4];
    const float* b2  = (const float*)d_in[5];
    const float* Wf1 = (const float*)d_in[6];
    const float* bf1 = (const float*)d_in[7];
    const float* Wf2 = (const float*)d_in[8];
    const float* bf2 = (const float*)d_in[9];
    const float* Wf3 = (const float*)d_in[10];
    const float* bf3 = (const float*)d_in[11];
    float* ws  = (float*)d_ws;
    float* out = (float*)d_out;

    hipLaunchKernelGGL(prep_kernel, dim3(179), dim3(256), 0, stream,
                       f, geo, W1, b1, W2, b2, Wf1, ws);
    hipLaunchKernelGGL(megaconv_kernel, dim3(NBC), dim3(256), 0, stream,
                       f, geo, ws + UT_OFF,
                       reinterpret_cast<const float4*>(ws + G4_OFF),
                       reinterpret_cast<const float4*>(ws + WF1T_OFF),
                       ws, bf1, Wf2, bf2, Wf3, bf3, out);
}

// Round 15
// 27.434 us; speedup vs baseline: 3.1752x; 1.2114x over previous
//
#include <hip/hip_runtime.h>

#define Nn 1024
#define Cc 23
#define Hh 100
#define KN 64                  // knots over v=r/1.5 in [0,3], 63 cells
#define DSTR 68                // lds_d row stride (64 + pad)
#define MUSCALE 14.0f          // (63/3)/1.5  (mu = r * MUSCALE)
#define MUCLAMP 62.999f
#define NBC 2048               // conv blocks: z(4) x ah(8) x s(64)

// ws float offsets
#define UT_OFF     0           // U transposed [23][64] = 1472
#define G4_OFF     1536        // [4096][4] = 16384
#define WF1T_OFF   17920       // Wf1^T / 32  [30][1024] = 30720
#define BIAS_OFF   48640       // [4]
#define COLSUM_OFF 48644       // [30]
#define D_OFF      48704       // D[4096][64] = 262144
#define PB_OFF     310912      // [30][2048] fc1 partials = 61440
#define X1PRE_OFF  372352      // [30][4]

__device__ __forceinline__ float rdlane(float v, int l) {
    return __int_as_float(__builtin_amdgcn_readlane(__float_as_int(v), l));
}

// ---------------------------------------------------------------------------
// K0: 115 blocks. 0..63: U_T[c][k]; 64..79: geom4; 80..83: bias[z];
// 84: colsum; 85..114: Wf1T[d][k] = Wf1[k][d]/32
// ---------------------------------------------------------------------------
__global__ __launch_bounds__(256)
void prep_kernel(const float* __restrict__ f,
                 const float* __restrict__ geom,
                 const float* __restrict__ W1,
                 const float* __restrict__ b1,
                 const float* __restrict__ W2,
                 const float* __restrict__ b2,
                 const float* __restrict__ Wf1,
                 float* __restrict__ ws) {
    int blk = blockIdx.x;
    int t = threadIdx.x;
    if (blk < 64) {                        // one knot per block
        __shared__ float w2s[Hh * Cc];
        __shared__ float hv_s[Hh];
        int k = blk;
        for (int j = t; j < Hh * Cc; j += 256) w2s[j] = W2[j];
        if (t < Hh) {
            float v = (float)k * (3.0f / 63.0f);
            const float HPI = 1.57079632679f;
            float c0 = cosf(HPI * v);
            float c1 = cosf(HPI * (v - 1.0f));
            float c2 = cosf(HPI * (v - 2.0f));
            float s0 = (v < 1.0f) ? c0 * c0 : 0.0f;
            float s1 = (fabsf(v - 1.0f) < 1.0f) ? c1 * c1 : 0.0f;
            float s2 = (v > 1.0f && v < 3.0f) ? c2 * c2 : 0.0f;
            float pre = fmaf(s0, W1[t],
                         fmaf(s1, W1[Hh + t],
                          fmaf(s2, W1[2 * Hh + t], b1[t])));
            hv_s[t] = fmaxf(pre, 0.f);
        }
        __syncthreads();
        if (t < Cc) {
            float a0 = 0.f, a1 = 0.f;
            #pragma unroll 4
            for (int h = 0; h < Hh; h += 2) {
                a0 = fmaf(hv_s[h],     w2s[h * Cc + t],       a0);
                a1 = fmaf(hv_s[h + 1], w2s[(h + 1) * Cc + t], a1);
            }
            ws[UT_OFF + t * KN + k] = a0 + a1;
        }
    } else if (blk < 80) {                 // geom4 pack
        int zb = (blk - 64) * 256 + t;
        const float* g = geom + zb * 3;
        reinterpret_cast<float4*>(ws + G4_OFF)[zb] =
            make_float4(g[0], g[1], g[2], 0.f);
    } else if (blk < 84) {                 // bias[z]
        __shared__ float red[256];
        int z = blk - 80;
        float s = 0.f;
        #pragma unroll
        for (int rr = 0; rr < 4; ++rr) {
            const float* fr = f + ((z << 10) + rr * 256 + t) * Cc;
            #pragma unroll
            for (int c = 0; c < Cc; ++c) s = fmaf(fr[c], b2[c], s);
        }
        red[t] = s; __syncthreads();
        for (int off = 128; off; off >>= 1) {
            if (t < off) red[t] += red[t + off];
            __syncthreads();
        }
        if (t == 0) ws[BIAS_OFF + z] = red[0];
    } else if (blk == 84) {                // colsum[d]
        __shared__ float cs_s[240];
        if (t < 240) {
            int d = t % 30, oct = t / 30;
            float c0 = 0.f, c1 = 0.f;
            #pragma unroll 4
            for (int j = 0; j < 128; j += 2) {
                c0 += Wf1[(oct * 128 + j) * 30 + d];
                c1 += Wf1[(oct * 128 + j + 1) * 30 + d];
            }
            cs_s[t] = c0 + c1;
        }
        __syncthreads();
        if (t < 30) {
            float cs = 0.f;
            #pragma unroll
            for (int o = 0; o < 8; ++o) cs += cs_s[o * 30 + t];
            ws[COLSUM_OFF + t] = cs;
        }
    } else {                               // Wf1T, one d per block
        int d = blk - 85;
        #pragma unroll
        for (int j = 0; j < 4; ++j) {
            int k = j * 256 + t;
            ws[WF1T_OFF + d * Nn + k] = Wf1[k * 30 + d] * 0.03125f;
        }
    }
}

// ---------------------------------------------------------------------------
// K1: dgemm — D[row][k] = sum_c UT[c][k]*f[row][c]. 256 blocks x 256 thr;
// wave = 4 rows, k = lane (KN=64). Coalesced UT loads, readlane f broadcasts.
// ---------------------------------------------------------------------------
__global__ __launch_bounds__(256)
void dgemm_kernel(const float* __restrict__ f,
                  const float* __restrict__ ut,    // ws + UT_OFF
                  float* __restrict__ D) {         // ws + D_OFF
    const int t = threadIdx.x;
    const int lane = t & 63;
    const int wv = __builtin_amdgcn_readfirstlane(t >> 6);
    float ur[Cc];
    #pragma unroll
    for (int c = 0; c < Cc; ++c) ur[c] = ut[c * KN + lane];
    const int row0 = blockIdx.x * 16 + wv * 4;
    float fr[2];                           // 4 rows x 23 = 92 floats
    {
        int base = row0 * Cc;
        fr[0] = f[base + lane];
        int o2 = 64 + lane; if (o2 > 91) o2 = 91;
        fr[1] = f[base + o2];
    }
    #pragma unroll
    for (int r = 0; r < 4; ++r) {
        float a0 = 0.f, a1 = 0.f, a2 = 0.f, a3 = 0.f;
        #pragma unroll
        for (int c = 0; c < 20; c += 4) {
            a0 = fmaf(rdlane(fr[(r * Cc + c + 0) >> 6], (r * Cc + c + 0) & 63), ur[c + 0], a0);
            a1 = fmaf(rdlane(fr[(r * Cc + c + 1) >> 6], (r * Cc + c + 1) & 63), ur[c + 1], a1);
            a2 = fmaf(rdlane(fr[(r * Cc + c + 2) >> 6], (r * Cc + c + 2) & 63), ur[c + 2], a2);
            a3 = fmaf(rdlane(fr[(r * Cc + c + 3) >> 6], (r * Cc + c + 3) & 63), ur[c + 3], a3);
        }
        a0 = fmaf(rdlane(fr[(r * Cc + 20) >> 6], (r * Cc + 20) & 63), ur[20], a0);
        a1 = fmaf(rdlane(fr[(r * Cc + 21) >> 6], (r * Cc + 21) & 63), ur[21], a1);
        a2 = fmaf(rdlane(fr[(r * Cc + 22) >> 6], (r * Cc + 22) & 63), ur[22], a2);
        D[(row0 + r) * KN + lane] = (a0 + a1) + (a2 + a3);
    }
}

// ---------------------------------------------------------------------------
// K2: conv + fc1 fold. 2048 blocks x 128 thr (8 blocks/CU, 16 waves/CU).
// Block (z, ah, s): a-range ah*128..+127 (1 per thread), b-range s*16..+15.
// Stage D-tile (16x64) -> LDS; 16 gather-lerp edges/thread; fold via float2
// Wf1T -> plain store pb[d][z*512 + ah*64 + s].
// ---------------------------------------------------------------------------
__global__ __launch_bounds__(128, 4)
void conv_kernel(const float* __restrict__ geom,
                 const float* __restrict__ Dg,       // ws + D_OFF
                 const float4* __restrict__ geom4,   // ws + G4_OFF
                 const float2* __restrict__ wf1t2,   // ws + WF1T_OFF
                 float* __restrict__ pb) {           // ws + PB_OFF
    __shared__ float lds_d[16 * DSTR];   // 4352 B
    __shared__ float lds_acc[128];
    const int bid = blockIdx.x;
    const int t = threadIdx.x;
    const int lane = t & 63;
    const int wv = __builtin_amdgcn_readfirstlane(t >> 6);
    const int z = bid >> 9;
    const int ah = (bid >> 6) & 7;
    const int s = bid & 63;
    const int b0 = s * 16;

    // stage D-tile: 16 rows x 16 float4, 2 rounds, coalesced
    {
        const float4* src = reinterpret_cast<const float4*>(Dg + ((z << 10) + b0) * KN);
        #pragma unroll
        for (int j = t; j < 256; j += 128) {
            int row = j >> 4, k4 = j & 15;
            reinterpret_cast<float4*>(lds_d)[row * 17 + k4] = src[j];
        }
    }
    float gr;                              // 16 b-geometries (48 floats)
    {
        int off = lane < 48 ? lane : 47;
        gr = geom[((z << 10) + b0) * 3 + off];
    }
    float4 ga = geom4[(z << 10) + (ah << 7) + t];
    __syncthreads();

    // edges: thread owns a = ah*128 + t; 16 b's
    float acc = 0.f;
    #pragma unroll
    for (int bl = 0; bl < 16; ++bl) {
        float dx = ga.x - rdlane(gr, bl * 3 + 0);
        float dy = ga.y - rdlane(gr, bl * 3 + 1);
        float dz = ga.z - rdlane(gr, bl * 3 + 2);
        float r = sqrtf(fmaf(dx, dx, fmaf(dy, dy, fmaf(dz, dz, 1e-12f))));
        float mu = fminf(r * MUSCALE, MUCLAMP);
        int m = (int)mu;
        float tt = mu - (float)m;
        const float* row = lds_d + bl * DSTR + m;
        float d0 = row[0];
        float d1 = row[1];
        acc += fmaf(tt, d1 - d0, d0);
    }
    lds_acc[t] = acc;
    __syncthreads();

    // fold: wave wv handles d = wv*15 .. wv*15+14; lane covers 2 a's
    {
        const float2* a2 = reinterpret_cast<const float2*>(lds_acc);
        float2 av = a2[lane];
        #pragma unroll
        for (int i = 0; i < 15; ++i) {
            int d = wv * 15 + i;
            float2 w = wf1t2[d * 512 + (ah << 6) + lane];
            float sum = av.x * w.x + av.y * w.y;
            #pragma unroll
            for (int off = 32; off; off >>= 1) sum += __shfl_down(sum, off);
            if (lane == 0) pb[d * NBC + (z << 9) + (ah << 6) + s] = sum;
        }
    }
}

// ---------------------------------------------------------------------------
// K3: head1 — 30 blocks (one d each); wave = z, 8 floats/lane, shfl-reduce.
// ---------------------------------------------------------------------------
__global__ __launch_bounds__(256)
void head1_kernel(const float* __restrict__ pb,     // ws + PB_OFF
                  float* __restrict__ x1pre) {      // ws + X1PRE_OFF
    int d = blockIdx.x;
    int t = threadIdx.x;
    int z = t >> 6, lane = t & 63;
    const float4* p4 = reinterpret_cast<const float4*>(pb + d * NBC + (z << 9));
    float4 v0 = p4[lane * 2];
    float4 v1 = p4[lane * 2 + 1];
    float s = ((v0.x + v0.y) + (v0.z + v0.w)) + ((v1.x + v1.y) + (v1.z + v1.w));
    #pragma unroll
    for (int off = 32; off; off >>= 1) s += __shfl_down(s, off);
    if (lane == 0) x1pre[d * 4 + z] = s;
}

// ---------------------------------------------------------------------------
// K4: fc23 — x1 = relu(x1pre + bias*colsum/32 + bf1), fc2 relu, fc3.
// ---------------------------------------------------------------------------
__global__ __launch_bounds__(128)
void fc23_kernel(const float* __restrict__ ws,
                 const float* __restrict__ bf1,
                 const float* __restrict__ Wf2, const float* __restrict__ bf2,
                 const float* __restrict__ Wf3, const float* __restrict__ bf3,
                 float* __restrict__ out) {
    __shared__ float x1s[120];
    __shared__ float x2s[40];
    int t = threadIdx.x;
    if (t < 120) {
        int d = t >> 2, zz = t & 3;
        float x1 = ws[X1PRE_OFF + t]
                 + ws[BIAS_OFF + zz] * 0.03125f * ws[COLSUM_OFF + d]
                 + bf1[d];
        x1s[zz * 30 + d] = fmaxf(x1, 0.f);
    }
    __syncthreads();
    if (t < 40) {
        int zz = t / 10, d = t % 10;
        float sm = bf2[d];
        #pragma unroll
        for (int kk = 0; kk < 30; ++kk)
            sm = fmaf(x1s[zz * 30 + kk], Wf2[kk * 10 + d], sm);
        x2s[t] = fmaxf(sm, 0.f);
    }
    __syncthreads();
    if (t < 4) {
        float sm = bf3[0];
        #pragma unroll
        for (int kk = 0; kk < 10; ++kk)
            sm = fmaf(x2s[t * 10 + kk], Wf3[kk], sm);
        out[t] = sm;
    }
}

extern "C" void kernel_launch(void* const* d_in, const int* in_sizes, int n_in,
                              void* d_out, int out_size, void* d_ws, size_t ws_size,
                              hipStream_t stream) {
    const float* f   = (const float*)d_in[0];
    const float* geo = (const float*)d_in[1];
    const float* W1  = (const float*)d_in[2];
    const float* b1  = (const float*)d_in[3];
    const float* W2  = (const float*)d_in[4];
    const float* b2  = (const float*)d_in[5];
    const float* Wf1 = (const float*)d_in[6];
    const float* bf1 = (const float*)d_in[7];
    const float* Wf2 = (const float*)d_in[8];
    const float* bf2 = (const float*)d_in[9];
    const float* Wf3 = (const float*)d_in[10];
    const float* bf3 = (const float*)d_in[11];
    float* ws  = (float*)d_ws;
    float* out = (float*)d_out;

    hipLaunchKernelGGL(prep_kernel, dim3(115), dim3(256), 0, stream,
                       f, geo, W1, b1, W2, b2, Wf1, ws);
    hipLaunchKernelGGL(dgemm_kernel, dim3(256), dim3(256), 0, stream,
                       f, ws + UT_OFF, ws + D_OFF);
    hipLaunchKernelGGL(conv_kernel, dim3(NBC), dim3(128), 0, stream,
                       geo, ws + D_OFF,
                       reinterpret_cast<const float4*>(ws + G4_OFF),
                       reinterpret_cast<const float2*>(ws + WF1T_OFF),
                       ws + PB_OFF);
    hipLaunchKernelGGL(head1_kernel, dim3(30), dim3(256), 0, stream,
                       ws + PB_OFF, ws + X1PRE_OFF);
    hipLaunchKernelGGL(fc23_kernel, dim3(1), dim3(128), 0, stream,
                       ws, bf1, Wf2, bf2, Wf3, bf3, out);
}